// Round 1
// baseline (1677.593 us; speedup 1.0000x reference)
//
#include <hip/hip_runtime.h>
#include <math.h>

// ---------------------------------------------------------------------------
// RNNDecoder step: embed -> Bahdanau attention -> LSTM cell -> vocab proj
// V=32000 E=512 H=1024 BS=128 SL=256
// All matmuls via bf16 MFMA 16x16x32 (fp32 inputs converted during LDS stage).
// ---------------------------------------------------------------------------

typedef __attribute__((ext_vector_type(8)))  __bf16 bf16x8;
typedef __attribute__((ext_vector_type(4)))  float  f32x4;

__device__ __forceinline__ unsigned short f2bf(float x) {
    unsigned int u = __float_as_uint(x);
    u += 0x7FFFu + ((u >> 16) & 1u);           // round-to-nearest-even
    return (unsigned short)(u >> 16);
}
__device__ __forceinline__ float sigm(float x) { return 1.0f / (1.0f + expf(-x)); }

// ---------------------------------------------------------------------------
// Templated bf16 MFMA GEMM.  C[m][n] = sum_k A[m][k] * B[n][k]   (B given n-major)
// MODE 0: plain store (h_proj)
// MODE 1: scores epilogue: atomicAdd_m( sum_n v[n]*tanh(acc + hproj[b][n] + attn_b[n]) )
// MODE 2: gates partial: store to C + blockIdx.z*128*4096 ; B split w_ih/w_hh at k=2560
// MODE 3: fco: store acc + bias[n]
// ---------------------------------------------------------------------------
template<int MODE, int BM, int BN, int WM, int WN, int NWM, int NWN>
__global__ __launch_bounds__(NWM * NWN * 64, 2)
void gemm_k(const float* __restrict__ A, int lda,
            const float* __restrict__ B, int ldb, int coff,
            const float* __restrict__ B2,
            float* __restrict__ C, int ldc,
            const float* __restrict__ ep0,
            const float* __restrict__ ep1,
            const float* __restrict__ ep2,
            int kc)
{
    constexpr int NT  = NWM * NWN * 64;
    constexpr int LDK = 48;                 // padded bf16 stride (96B rows: 16B-aligned frags)
    constexpr int NMT = WM / 16, NNT = WN / 16;

    __shared__ __align__(16) unsigned short As[BM * LDK];
    __shared__ __align__(16) unsigned short Bs[BN * LDK];

    const int t    = threadIdx.x;
    const int n0   = blockIdx.x * BN;
    const int m0   = blockIdx.y * BM;
    const int k0c  = blockIdx.z * kc;

    const int wave = t >> 6, lane = t & 63;
    const int lrow = lane & 15, quad = lane >> 4;
    const int wm0  = (wave / NWN) * WM;
    const int wn0  = (wave % NWN) * WN;

    f32x4 acc[NMT][NNT];
#pragma unroll
    for (int i = 0; i < NMT; ++i)
#pragma unroll
        for (int j = 0; j < NNT; ++j) acc[i][j] = f32x4{0.f, 0.f, 0.f, 0.f};

    const int niter = kc >> 5;              // BK = 32
    for (int kt = 0; kt < niter; ++kt) {
        const int kcur = k0c + (kt << 5);
        __syncthreads();
        // ---- stage A tile (BM x 32) fp32 -> bf16 ----
#pragma unroll
        for (int i = t; i < BM * 8; i += NT) {
            const int r = i >> 3, kq = i & 7;
            const float4 v = *(const float4*)(A + (size_t)(m0 + r) * lda + kcur + kq * 4);
            ushort4 h;
            h.x = f2bf(v.x); h.y = f2bf(v.y); h.z = f2bf(v.z); h.w = f2bf(v.w);
            *(ushort4*)(&As[r * LDK + kq * 4]) = h;
        }
        // ---- stage B tile (BN x 32) fp32 -> bf16 ----
#pragma unroll
        for (int i = t; i < BN * 8; i += NT) {
            const int r = i >> 3, kq = i & 7;
            const int kg = kcur + kq * 4;
            const float* src;
            if constexpr (MODE == 2) {
                src = (kg < 2560) ? (B  + (size_t)(n0 + r) * 2560 + kg)
                                  : (B2 + (size_t)(n0 + r) * 1024 + (kg - 2560));
            } else {
                src = B + (size_t)(n0 + r) * ldb + coff + kg;
            }
            const float4 v = *(const float4*)src;
            ushort4 h;
            h.x = f2bf(v.x); h.y = f2bf(v.y); h.z = f2bf(v.z); h.w = f2bf(v.w);
            *(ushort4*)(&Bs[r * LDK + kq * 4]) = h;
        }
        __syncthreads();

        bf16x8 af[NMT];
#pragma unroll
        for (int mt = 0; mt < NMT; ++mt)
            af[mt] = *(const bf16x8*)(&As[(wm0 + mt * 16 + lrow) * LDK + quad * 8]);
#pragma unroll
        for (int nt = 0; nt < NNT; ++nt) {
            const bf16x8 bfr = *(const bf16x8*)(&Bs[(wn0 + nt * 16 + lrow) * LDK + quad * 8]);
#pragma unroll
            for (int mt = 0; mt < NMT; ++mt)
                acc[mt][nt] = __builtin_amdgcn_mfma_f32_16x16x32_bf16(af[mt], bfr, acc[mt][nt], 0, 0, 0);
        }
    }

    // ---- epilogue ----  D layout: col = lane&15, row = quad*4 + r
    if constexpr (MODE == 1) {
        const int b = m0 >> 8;              // BM=128 block lies inside one batch (SL=256)
        float part[NMT][4];
#pragma unroll
        for (int mt = 0; mt < NMT; ++mt) { part[mt][0] = part[mt][1] = part[mt][2] = part[mt][3] = 0.f; }
#pragma unroll
        for (int nt = 0; nt < NNT; ++nt) {
            const int gn = n0 + wn0 + nt * 16 + lrow;
            const float hb = ep0[b * 1024 + gn] + ep1[gn];
            const float vv = ep2[gn];
#pragma unroll
            for (int mt = 0; mt < NMT; ++mt)
#pragma unroll
                for (int r = 0; r < 4; ++r)
                    part[mt][r] += vv * tanhf(acc[mt][nt][r] + hb);
        }
#pragma unroll
        for (int mt = 0; mt < NMT; ++mt)
#pragma unroll
            for (int r = 0; r < 4; ++r) {
                float s = part[mt][r];
                s += __shfl_xor(s, 1); s += __shfl_xor(s, 2);
                s += __shfl_xor(s, 4); s += __shfl_xor(s, 8);
                if (lrow == 0)
                    atomicAdd(&C[m0 + wm0 + mt * 16 + quad * 4 + r], s);
            }
    } else {
        float* Cw = C;
        if constexpr (MODE == 2) Cw += (size_t)blockIdx.z * (size_t)(128 * 4096);
#pragma unroll
        for (int mt = 0; mt < NMT; ++mt)
#pragma unroll
            for (int nt = 0; nt < NNT; ++nt)
#pragma unroll
                for (int r = 0; r < 4; ++r) {
                    const int gm = m0 + wm0 + mt * 16 + quad * 4 + r;
                    const int gn = n0 + wn0 + nt * 16 + lrow;
                    float v = acc[mt][nt][r];
                    if constexpr (MODE == 3) v += ep0[gn];
                    Cw[(size_t)gm * ldc + gn] = v;
                }
    }
}

// ---------------------------------------------------------------------------
// embed lookup + h_top copy into concat buffers
// xh     = [embedded(0:512) | weighted(512:2560) | h_top(2560:3584)]
// outcat = [h_new(0:1024)   | weighted(1024:3072)| embedded(3072:3584)]
// ---------------------------------------------------------------------------
__global__ __launch_bounds__(256) void prep(const int* __restrict__ tok,
                                            const float* __restrict__ emb,
                                            const float* __restrict__ h0,
                                            float* __restrict__ xh,
                                            float* __restrict__ outcat)
{
    const int idx = blockIdx.x * 256 + threadIdx.x;   // 128*1536
    const int b = idx / 1536, j = idx - b * 1536;
    if (j < 512) {
        const float e = emb[(size_t)tok[b] * 512 + j];
        xh[b * 3584 + j]            = e;
        outcat[b * 3584 + 3072 + j] = e;
    } else {
        const int d = j - 512;
        xh[b * 3584 + 2560 + d] = h0[b * 1024 + d];
    }
}

// ---------------------------------------------------------------------------
// softmax over SL=256 per batch + weighted = a @ eo. grid = 128 batches x 8 d-chunks
// ---------------------------------------------------------------------------
__global__ __launch_bounds__(256) void attn_soft(const float* __restrict__ scores,
                                                 const float* __restrict__ eo,
                                                 float* __restrict__ xh,
                                                 float* __restrict__ outcat)
{
    const int b = blockIdx.x >> 3, q = blockIdx.x & 7, t = threadIdx.x;
    __shared__ float red[256];
    __shared__ float sm[256];

    const float sc = scores[b * 256 + t];
    red[t] = sc; __syncthreads();
#pragma unroll
    for (int off = 128; off > 0; off >>= 1) {
        if (t < off) red[t] = fmaxf(red[t], red[t + off]);
        __syncthreads();
    }
    const float M = red[0]; __syncthreads();
    const float e = expf(sc - M);
    red[t] = e; __syncthreads();
#pragma unroll
    for (int off = 128; off > 0; off >>= 1) {
        if (t < off) red[t] += red[t + off];
        __syncthreads();
    }
    const float S = red[0];
    sm[t] = e / S;
    __syncthreads();

    const float* ep = eo + (size_t)b * 256 * 2048 + q * 256 + t;
    float acc = 0.f;
#pragma unroll 4
    for (int s = 0; s < 256; ++s) acc += sm[s] * ep[(size_t)s * 2048];

    const int d = q * 256 + t;
    xh[b * 3584 + 512 + d]      = acc;
    outcat[b * 3584 + 1024 + d] = acc;
}

// ---------------------------------------------------------------------------
// LSTM elementwise: sum 4 K-chunk partials + biases, gate order i,f,g,o
// ---------------------------------------------------------------------------
__global__ __launch_bounds__(256) void lstm_epi(const float* __restrict__ gp,
                                                const float* __restrict__ b_ih,
                                                const float* __restrict__ b_hh,
                                                const float* __restrict__ c0,
                                                float* __restrict__ outcat,
                                                float* __restrict__ hc)
{
    const int idx = blockIdx.x * 256 + threadIdx.x;   // 128*1024
    const int b = idx >> 10, j = idx & 1023;
    float g[4];
#pragma unroll
    for (int gi = 0; gi < 4; ++gi) {
        const int col = gi * 1024 + j;
        float s = b_ih[col] + b_hh[col];
#pragma unroll
        for (int kb = 0; kb < 4; ++kb) s += gp[kb * 524288 + b * 4096 + col];
        g[gi] = s;
    }
    const float c = sigm(g[1]) * c0[idx] + sigm(g[0]) * tanhf(g[2]);
    const float h = sigm(g[3]) * tanhf(c);
    outcat[b * 3584 + j] = h;
    hc[idx]           = h;     // h_new
    hc[131072 + idx]  = c;     // c_new
}

// ---------------------------------------------------------------------------
extern "C" void kernel_launch(void* const* d_in, const int* in_sizes, int n_in,
                              void* d_out, int out_size, void* d_ws, size_t ws_size,
                              hipStream_t stream)
{
    const int*   tok    = (const int*)  d_in[0];
    const float* h0     = (const float*)d_in[1];
    const float* c0     = (const float*)d_in[2];
    const float* eo     = (const float*)d_in[3];
    const float* emb_w  = (const float*)d_in[4];
    const float* attn_w = (const float*)d_in[5];
    const float* attn_b = (const float*)d_in[6];
    const float* v_w    = (const float*)d_in[7];
    const float* w_ih   = (const float*)d_in[8];
    const float* w_hh   = (const float*)d_in[9];
    const float* b_ih   = (const float*)d_in[10];
    const float* b_hh   = (const float*)d_in[11];
    const float* fco_w  = (const float*)d_in[12];
    const float* fco_b  = (const float*)d_in[13];
    float* out = (float*)d_out;

    float* w      = (float*)d_ws;
    float* scores = w;                 // 32768
    float* hproj  = w + 32768;         // 131072
    float* xh     = w + 163840;        // 458752
    float* outcat = w + 622592;        // 458752
    float* gparts = w + 1081344;       // 4 * 524288

    hipMemsetAsync(scores, 0, 32768 * sizeof(float), stream);
    prep<<<768, 256, 0, stream>>>(tok, emb_w, h0, xh, outcat);

    // h_proj[b][h] = h_top . attn_w[h, 0:1024]          M=128 N=1024 K=1024
    gemm_k<0, 128, 64, 64, 32, 2, 2><<<dim3(16, 1, 1), 256, 0, stream>>>(
        h0, 1024, attn_w, 3072, 0, nullptr, hproj, 1024, nullptr, nullptr, nullptr, 1024);

    // scores[m] += sum_n v[n]*tanh(eo[m].attn_w[n,1024:] + hproj + b)   M=32768 N=1024 K=2048
    gemm_k<1, 128, 512, 64, 128, 2, 4><<<dim3(2, 256, 1), 512, 0, stream>>>(
        eo, 2048, attn_w, 3072, 1024, nullptr, scores, 0, hproj, attn_b, v_w, 2048);

    attn_soft<<<1024, 256, 0, stream>>>(scores, eo, xh, outcat);

    // gates partials: xh . [w_ih | w_hh]^T               M=128 N=4096 K=3584 (4 k-chunks)
    gemm_k<2, 128, 64, 64, 32, 2, 2><<<dim3(64, 1, 4), 256, 0, stream>>>(
        xh, 3584, w_ih, 2560, 0, w_hh, gparts, 4096, nullptr, nullptr, nullptr, 896);

    lstm_epi<<<512, 256, 0, stream>>>(gparts, b_ih, b_hh, c0, outcat, out + 4096000);

    // prediction = outcat . fco_w^T + fco_b              M=128 N=32000 K=3584
    gemm_k<3, 128, 64, 64, 32, 2, 2><<<dim3(500, 1, 1), 256, 0, stream>>>(
        outcat, 3584, fco_w, 3584, 0, nullptr, out, 32000, fco_b, nullptr, nullptr, 3584);
}

// Round 2
// 1136.872 us; speedup vs baseline: 1.4756x; 1.4756x over previous
//
#include <hip/hip_runtime.h>
#include <math.h>

// V=32000 E=512 H=1024 BS=128 SL=256
typedef unsigned short u16;
typedef __attribute__((ext_vector_type(8))) __bf16 bf16x8;
typedef __attribute__((ext_vector_type(4))) float  f32x4;
typedef __attribute__((ext_vector_type(8))) unsigned short u16x8;

__device__ __forceinline__ u16 f2bf(float x) {
    unsigned u = __float_as_uint(x);
    u += 0x7FFFu + ((u >> 16) & 1u);      // RNE
    return (u16)(u >> 16);
}
__device__ __forceinline__ float b2f(u16 u) { return __uint_as_float(((unsigned)u) << 16); }
__device__ __forceinline__ float ftanh(float x) {
    x = fminf(fmaxf(x, -15.f), 15.f);
    const float e = __expf(2.f * x);
    return (e - 1.f) / (e + 1.f);
}
__device__ __forceinline__ float sigm(float x) { return 1.f / (1.f + __expf(-x)); }

__device__ __forceinline__ void gload16(const void* g, void* l) {
    __builtin_amdgcn_global_load_lds(
        (const __attribute__((address_space(1))) unsigned*)g,
        (__attribute__((address_space(3))) unsigned*)l, 16, 0, 0);
}

// ---------------------------------------------------------------------------
// bf16 MFMA GEMM, m97 structure: BK=32, unpadded LDS [rows][32] bf16,
// A16/B16 -> global_load_lds 16B; fp32 operands staged via VGPR+convert.
// MODE 1: scores epilogue  (atomicAdd_m sum_n v*tanh(acc+hproj+b))
// MODE 2: gates partials   (B split w_ih/w_hh at k=2560, store + z offset)
// MODE 3: fco              (store acc + bias)
// MODE 4: atomicAdd acc    (split-K hproj)
// ---------------------------------------------------------------------------
template<int MODE, int BM, int BN, int WGM, int WGN, bool A16, bool B16>
__global__ __launch_bounds__(WGM * WGN * 64, 4)
void gemm_k(const void* __restrict__ Ap, int lda,
            const void* __restrict__ Bp, int ldb,
            const float* __restrict__ B2,
            float* __restrict__ C, int ldc,
            const float* __restrict__ ep0,
            const float* __restrict__ ep1,
            const float* __restrict__ ep2,
            int kc)
{
    constexpr int NW = WGM * WGN, NT = NW * 64;
    constexpr int WM = BM / WGM, WN = BN / WGN;
    constexpr int NMT = WM / 16, NNT = WN / 16;

    __shared__ __align__(16) u16 As[BM * 32];
    __shared__ __align__(16) u16 Bs[BN * 32];

    const int t    = threadIdx.x;
    const int n0   = blockIdx.x * BN;
    const int m0   = blockIdx.y * BM;
    const int k0c  = blockIdx.z * kc;
    const int wave = t >> 6, lane = t & 63;
    const int lrow = lane & 15, quad = lane >> 4;
    const int wm0  = (wave / WGN) * WM;
    const int wn0  = (wave % WGN) * WN;

    f32x4 acc[NMT][NNT];
#pragma unroll
    for (int i = 0; i < NMT; ++i)
#pragma unroll
        for (int j = 0; j < NNT; ++j) acc[i][j] = f32x4{0.f, 0.f, 0.f, 0.f};

    const int niter = kc >> 5;
    for (int kt = 0; kt < niter; ++kt) {
        const int kcur = k0c + (kt << 5);
        __syncthreads();
        // ---- stage A (BM x 32) ----
        if constexpr (A16) {
            const u16* Ab = (const u16*)Ap;
#pragma unroll
            for (int c = t; c < BM * 4; c += NT)
                gload16(Ab + (size_t)(m0 + (c >> 2)) * lda + kcur + (c & 3) * 8, &As[c * 8]);
        } else {
            const float* Af = (const float*)Ap;
#pragma unroll
            for (int c = t; c < BM * 8; c += NT) {
                const int r = c >> 3, c4 = c & 7;
                const float4 v = *(const float4*)(Af + (size_t)(m0 + r) * lda + kcur + c4 * 4);
                ushort4 h; h.x = f2bf(v.x); h.y = f2bf(v.y); h.z = f2bf(v.z); h.w = f2bf(v.w);
                *(ushort4*)(&As[r * 32 + c4 * 4]) = h;
            }
        }
        // ---- stage B (BN x 32) ----
        if constexpr (B16) {
            const u16* Bb = (const u16*)Bp;
#pragma unroll
            for (int c = t; c < BN * 4; c += NT)
                gload16(Bb + (size_t)(n0 + (c >> 2)) * ldb + kcur + (c & 3) * 8, &Bs[c * 8]);
        } else {
#pragma unroll
            for (int c = t; c < BN * 8; c += NT) {
                const int r = c >> 3, c4 = c & 7;
                const int kg = kcur + c4 * 4;
                const float* src;
                if constexpr (MODE == 2)
                    src = (kg < 2560) ? ((const float*)Bp + (size_t)(n0 + r) * 2560 + kg)
                                      : (B2 + (size_t)(n0 + r) * 1024 + (kg - 2560));
                else
                    src = (const float*)Bp + (size_t)(n0 + r) * ldb + kg;
                const float4 v = *(const float4*)src;
                ushort4 h; h.x = f2bf(v.x); h.y = f2bf(v.y); h.z = f2bf(v.z); h.w = f2bf(v.w);
                *(ushort4*)(&Bs[r * 32 + c4 * 4]) = h;
            }
        }
        __syncthreads();

        bf16x8 af[NMT];
#pragma unroll
        for (int mt = 0; mt < NMT; ++mt)
            af[mt] = *(const bf16x8*)(&As[(wm0 + mt * 16 + lrow) * 32 + quad * 8]);
#pragma unroll
        for (int nt = 0; nt < NNT; ++nt) {
            const bf16x8 bfr = *(const bf16x8*)(&Bs[(wn0 + nt * 16 + lrow) * 32 + quad * 8]);
#pragma unroll
            for (int mt = 0; mt < NMT; ++mt)
                acc[mt][nt] = __builtin_amdgcn_mfma_f32_16x16x32_bf16(af[mt], bfr, acc[mt][nt], 0, 0, 0);
        }
    }

    // ---- epilogue ----  D layout: col = lane&15, row = quad*4 + r
    if constexpr (MODE == 1) {
        const int b = m0 >> 8;
        float part[NMT][4];
#pragma unroll
        for (int mt = 0; mt < NMT; ++mt) { part[mt][0] = part[mt][1] = part[mt][2] = part[mt][3] = 0.f; }
#pragma unroll
        for (int nt = 0; nt < NNT; ++nt) {
            const int gn = n0 + wn0 + nt * 16 + lrow;
            const float hb = ep0[b * 1024 + gn] + ep1[gn];
            const float vv = ep2[gn];
#pragma unroll
            for (int mt = 0; mt < NMT; ++mt)
#pragma unroll
                for (int r = 0; r < 4; ++r)
                    part[mt][r] += vv * ftanh(acc[mt][nt][r] + hb);
        }
#pragma unroll
        for (int mt = 0; mt < NMT; ++mt)
#pragma unroll
            for (int r = 0; r < 4; ++r) {
                float s = part[mt][r];
                s += __shfl_xor(s, 1); s += __shfl_xor(s, 2);
                s += __shfl_xor(s, 4); s += __shfl_xor(s, 8);
                if (lrow == 0)
                    atomicAdd(&C[m0 + wm0 + mt * 16 + quad * 4 + r], s);
            }
    } else {
        float* Cw = C;
        if constexpr (MODE == 2) Cw += (size_t)blockIdx.z * (size_t)(128 * 4096);
#pragma unroll
        for (int mt = 0; mt < NMT; ++mt)
#pragma unroll
            for (int nt = 0; nt < NNT; ++nt)
#pragma unroll
                for (int r = 0; r < 4; ++r) {
                    const int gm = m0 + wm0 + mt * 16 + quad * 4 + r;
                    const int gn = n0 + wn0 + nt * 16 + lrow;
                    float v = acc[mt][nt][r];
                    if constexpr (MODE == 3) v += ep0[gn];
                    if constexpr (MODE == 4) atomicAdd(&Cw[(size_t)gm * ldc + gn], v);
                    else                     Cw[(size_t)gm * ldc + gn] = v;
                }
    }
}

// ---------------------------------------------------------------------------
__global__ __launch_bounds__(256) void conv_eo(const float* __restrict__ s, u16* __restrict__ d) {
    const size_t i = ((size_t)blockIdx.x * 256 + threadIdx.x) * 8;
    const float4 a = *(const float4*)(s + i);
    const float4 b = *(const float4*)(s + i + 4);
    u16x8 o;
    o[0] = f2bf(a.x); o[1] = f2bf(a.y); o[2] = f2bf(a.z); o[3] = f2bf(a.w);
    o[4] = f2bf(b.x); o[5] = f2bf(b.y); o[6] = f2bf(b.z); o[7] = f2bf(b.w);
    *(u16x8*)(d + i) = o;
}

__global__ __launch_bounds__(256) void conv_w(const float* __restrict__ aw,
                                              u16* __restrict__ wHP, u16* __restrict__ wEO) {
    const int c = blockIdx.x * 256 + threadIdx.x;     // 1024*384
    const int row = c / 384, cc = (c - row * 384) * 8;
    const float* s = aw + (size_t)row * 3072 + cc;
    const float4 a = *(const float4*)s;
    const float4 b = *(const float4*)(s + 4);
    u16x8 o;
    o[0] = f2bf(a.x); o[1] = f2bf(a.y); o[2] = f2bf(a.z); o[3] = f2bf(a.w);
    o[4] = f2bf(b.x); o[5] = f2bf(b.y); o[6] = f2bf(b.z); o[7] = f2bf(b.w);
    if (cc < 1024) *(u16x8*)(wHP + (size_t)row * 1024 + cc) = o;
    else           *(u16x8*)(wEO + (size_t)row * 2048 + (cc - 1024)) = o;
}

// xh16 = [embedded | weighted | h_top], oc16 = [h_new | weighted | embedded]
__global__ __launch_bounds__(256) void prep(const int* __restrict__ tok,
                                            const float* __restrict__ emb,
                                            const float* __restrict__ h0,
                                            u16* __restrict__ xh, u16* __restrict__ oc) {
    const int idx = blockIdx.x * 256 + threadIdx.x;   // 128*1536
    const int b = idx / 1536, j = idx - b * 1536;
    if (j < 512) {
        const u16 e = f2bf(emb[(size_t)tok[b] * 512 + j]);
        xh[b * 3584 + j] = e;
        oc[b * 3584 + 3072 + j] = e;
    } else {
        const int d = j - 512;
        xh[b * 3584 + 2560 + d] = f2bf(h0[b * 1024 + d]);
    }
}

template<typename T>
__global__ __launch_bounds__(256) void attn_soft(const float* __restrict__ scores,
                                                 const T* __restrict__ eo,
                                                 u16* __restrict__ xh, u16* __restrict__ oc) {
    const int b = blockIdx.x >> 3, q = blockIdx.x & 7, t = threadIdx.x;
    __shared__ float red[256];
    __shared__ float sm[256];
    const float sc = scores[b * 256 + t];
    red[t] = sc; __syncthreads();
#pragma unroll
    for (int off = 128; off > 0; off >>= 1) {
        if (t < off) red[t] = fmaxf(red[t], red[t + off]);
        __syncthreads();
    }
    const float M = red[0]; __syncthreads();
    const float e = __expf(sc - M);
    red[t] = e; __syncthreads();
#pragma unroll
    for (int off = 128; off > 0; off >>= 1) {
        if (t < off) red[t] += red[t + off];
        __syncthreads();
    }
    const float S = red[0];
    sm[t] = e / S;
    __syncthreads();

    const T* ep = eo + (size_t)b * 256 * 2048 + q * 256 + t;
    float acc = 0.f;
#pragma unroll 4
    for (int s = 0; s < 256; ++s) {
        float v;
        if constexpr (sizeof(T) == 2) v = b2f(((const u16*)ep)[(size_t)s * 2048]);
        else                          v = ((const float*)ep)[(size_t)s * 2048];
        acc += sm[s] * v;
    }
    const int d = q * 256 + t;
    const u16 o = f2bf(acc);
    xh[b * 3584 + 512 + d]  = o;
    oc[b * 3584 + 1024 + d] = o;
}

__global__ __launch_bounds__(256) void lstm_epi(const float* __restrict__ gp,
                                                const float* __restrict__ b_ih,
                                                const float* __restrict__ b_hh,
                                                const float* __restrict__ c0,
                                                u16* __restrict__ oc,
                                                float* __restrict__ hc) {
    const int idx = blockIdx.x * 256 + threadIdx.x;   // 128*1024
    const int b = idx >> 10, j = idx & 1023;
    float g[4];
#pragma unroll
    for (int gi = 0; gi < 4; ++gi) {
        const int col = gi * 1024 + j;
        float s = b_ih[col] + b_hh[col];
#pragma unroll
        for (int kb = 0; kb < 8; ++kb) s += gp[(size_t)kb * 524288 + b * 4096 + col];
        g[gi] = s;
    }
    const float c = sigm(g[1]) * c0[idx] + sigm(g[0]) * ftanh(g[2]);
    const float h = sigm(g[3]) * ftanh(c);
    oc[b * 3584 + j] = f2bf(h);
    hc[idx]          = h;
    hc[131072 + idx] = c;
}

// ---------------------------------------------------------------------------
extern "C" void kernel_launch(void* const* d_in, const int* in_sizes, int n_in,
                              void* d_out, int out_size, void* d_ws, size_t ws_size,
                              hipStream_t stream)
{
    const int*   tok    = (const int*)  d_in[0];
    const float* h0     = (const float*)d_in[1];
    const float* c0     = (const float*)d_in[2];
    const float* eo     = (const float*)d_in[3];
    const float* emb_w  = (const float*)d_in[4];
    const float* attn_w = (const float*)d_in[5];
    const float* attn_b = (const float*)d_in[6];
    const float* v_w    = (const float*)d_in[7];
    const float* w_ih   = (const float*)d_in[8];
    const float* w_hh   = (const float*)d_in[9];
    const float* b_ih   = (const float*)d_in[10];
    const float* b_hh   = (const float*)d_in[11];
    const float* fco_w  = (const float*)d_in[12];
    const float* fco_b  = (const float*)d_in[13];
    float* out = (float*)d_out;

    char*  w      = (char*)d_ws;
    float* scores = (float*)(w);                 // 128 KB
    float* hproj  = (float*)(w + 131072);        // 512 KB
    float* gparts = (float*)(w + 655360);        // 16 MB (8 x 128x4096 f32)
    u16*   xh16   = (u16*)  (w + 17432576);      // 128x3584
    u16*   oc16   = (u16*)  (w + 18350080);      // 128x3584
    u16*   wHP    = (u16*)  (w + 19267584);      // 1024x1024
    u16*   wEO    = (u16*)  (w + 21364736);      // 1024x2048
    u16*   eo16   = (u16*)  (w + 25559040);      // 32768x2048 (128 MB)
    const bool big = ws_size >= 159776768ull;

    hipMemsetAsync(w, 0, 655360, stream);        // scores + hproj
    prep<<<768, 256, 0, stream>>>(tok, emb_w, h0, xh16, oc16);
    conv_w<<<1536, 256, 0, stream>>>(attn_w, wHP, wEO);
    if (big) conv_eo<<<32768, 256, 0, stream>>>(eo, eo16);

    // hproj = h_top @ attn_w[:, :H]^T   M=128 N=1024 K=1024, split-K x4 atomic
    gemm_k<4, 128, 64, 2, 2, true, true><<<dim3(16, 1, 4), 256, 0, stream>>>(
        xh16 + 2560, 3584, wHP, 1024, nullptr, hproj, 1024, nullptr, nullptr, nullptr, 256);

    // scores  M=32768 N=1024 K=2048
    if (big)
        gemm_k<1, 128, 128, 2, 2, true, true><<<dim3(8, 256, 1), 256, 0, stream>>>(
            eo16, 2048, wEO, 2048, nullptr, scores, 0, hproj, attn_b, v_w, 2048);
    else
        gemm_k<1, 128, 128, 2, 2, false, true><<<dim3(8, 256, 1), 256, 0, stream>>>(
            eo, 2048, wEO, 2048, nullptr, scores, 0, hproj, attn_b, v_w, 2048);

    if (big) attn_soft<u16>  <<<1024, 256, 0, stream>>>(scores, eo16, xh16, oc16);
    else     attn_soft<float><<<1024, 256, 0, stream>>>(scores, eo,   xh16, oc16);

    // gates partials  M=128 N=4096 K=3584, split-K x8
    gemm_k<2, 128, 64, 2, 2, true, false><<<dim3(64, 1, 8), 256, 0, stream>>>(
        xh16, 3584, w_ih, 0, w_hh, gparts, 4096, nullptr, nullptr, nullptr, 448);

    lstm_epi<<<512, 256, 0, stream>>>(gparts, b_ih, b_hh, c0, oc16, out + 4096000);

    // prediction  M=128 N=32000 K=3584
    gemm_k<3, 128, 32, 4, 1, true, false><<<dim3(1000, 1, 1), 256, 0, stream>>>(
        oc16, 3584, fco_w, 3584, nullptr, out, 32000, fco_b, nullptr, nullptr, 3584);
}